// Round 3
// baseline (447.109 us; speedup 1.0000x reference)
//
#include <hip/hip_runtime.h>
#include <hip/hip_bf16.h>

using short8 = __attribute__((ext_vector_type(8))) short;
using f32x4  = __attribute__((ext_vector_type(4))) float;

typedef const __attribute__((address_space(1))) void* gvp;
typedef __attribute__((address_space(3))) void* lvp;

#define NB   64     // batch rows (M)
#define NTOK 32     // tokens per batch row
#define DD   384
#define NE   8      // experts
#define TK   8      // top-k
#define NC   1000
#define KD   3072   // K*D
#define ND   12288  // N*D

__device__ __forceinline__ float gelu_f(float x) {
  return 0.5f * x * (1.0f + erff(x * 0.70710678118654752440f));
}

// f32 -> bf16 round-to-nearest-even (bit trick)
__device__ __forceinline__ unsigned short f2bf(float f) {
  unsigned u = __float_as_uint(f);
  u += 0x7fffu + ((u >> 16) & 1u);
  return (unsigned short)(u >> 16);
}

// ---------------------------------------------------------------------------
// Routing: logits = x[b] @ emb^T, top-8 per (b,e) (softmax monotonic -> skip),
// gather sel[e][b][k*D+d] = bf16(x[b][I[b,e,k]][d]); also xb = bf16(x).
// ---------------------------------------------------------------------------
__global__ __launch_bounds__(256) void routing_kernel(
    const float* __restrict__ x, const float* __restrict__ emb,
    unsigned short* __restrict__ sel, unsigned short* __restrict__ xb)
{
  __shared__ float xs[NTOK][DD + 1];   // +1 pad: kill stride-384 bank conflicts
  __shared__ float es[NE][DD + 1];
  __shared__ float lg[NE][NTOK];
  __shared__ int   Is[NE][TK];
  const int b = blockIdx.x, tid = threadIdx.x;

  for (int i = tid; i < NTOK * DD; i += 256) xs[i / DD][i % DD] = x[(size_t)b * ND + i];
  for (int i = tid; i < NE * DD;   i += 256) es[i / DD][i % DD] = emb[i];
  __syncthreads();

  {
    const int e = tid >> 5, n = tid & 31;
    float s = 0.f;
    for (int d = 0; d < DD; ++d) s += xs[n][d] * es[e][d];
    lg[e][n] = s;
  }
  __syncthreads();

  if (tid < NE) {   // stable argmax x8: ties -> lowest index, matches lax.top_k
    const int e = tid;
    for (int k = 0; k < TK; ++k) {
      float best = lg[e][0]; int bi = 0;
      for (int n = 1; n < NTOK; ++n) { float v = lg[e][n]; if (v > best) { best = v; bi = n; } }
      Is[e][k] = bi;
      lg[e][bi] = -INFINITY;
    }
  }
  __syncthreads();

  for (int i = tid; i < NE * KD; i += 256) {
    const int e = i / KD, r = i % KD, k = r / DD, d = r % DD;
    const int n = Is[e][k];
    sel[((size_t)e * NB + b) * KD + r] = f2bf(xs[n][d]);
  }
  for (int i = tid; i < ND; i += 256) xb[(size_t)b * ND + i] = f2bf(xs[i / DD][i % DD]);
}

// ---------------------------------------------------------------------------
// Skinny GEMM v3: partial[z] = A(bf16,[64][K])[:, z-slice] @ W(f32 slice)
// Block tile 64x256, staging steps of 32 rows x 256 cols (32 KB), double-
// buffered (64 KB LDS, 2 blocks/CU). Each global_load_lds call stages ONE
// FULL 1KB row-segment per wave (DRAM page efficiency). 8-float rotation
// per 8-row group applied on the SOURCE address (linear LDS dest), matching
// rotation on the ds_read side -> exact 2-way bank aliasing (free).
// 4 waves split n (64 cols each, 4 subtiles of 16). f32 partials out.
// ---------------------------------------------------------------------------
template<int K, int N, int SPLIT, bool NGUARD>
__global__ __launch_bounds__(256) void gemm3(
    const unsigned short* __restrict__ A, const float* __restrict__ W,
    float* __restrict__ outp, const int nbatch)
{
  constexpr int KCH = K / SPLIT;
  constexpr int NSTEP = KCH / 32;
  __shared__ float lw[2][8192];      // [buf][32 rows x 256 cols] f32

  const int t = threadIdx.x;
  const int wv = t >> 6, lane = t & 63;
  const int n0 = blockIdx.x * 256;
  const int bt = blockIdx.y, z = blockIdx.z;

  const unsigned short* Ab = A + (size_t)bt * 64 * K + (size_t)z * KCH;
  const float*          Wb = W + (size_t)bt * (size_t)K * N;

  // ---- staging: wave wv fills rows wv*8 .. wv*8+7 of each 32-row step ----
  // call r: full row (wv*8+r), lane writes stored cols lane*4..+3;
  // source col = (lane*4 - rot(row)) & 255, rot(row) = (row>>3)*8 = wv*8
  const int scol = ((lane * 4) - wv * 8) & 255;
  const float* gsrc   = Wb + (size_t)(z * KCH + wv * 8) * N + n0 + scol;
  const float* glimit = Wb + (size_t)K * N - 4;   // OOB clamp (NGUARD)
  float* lbase = &lw[0][0] + (wv * 8) * 256 + lane * 4;

  auto stage = [&](int bf, int st) {
    const float* g = gsrc + (size_t)st * 32 * N;
    float* l = lbase + bf * 8192;
    #pragma unroll
    for (int r = 0; r < 8; ++r) {
      const float* gp = g + (size_t)r * N;
      if (NGUARD && gp > glimit) gp = glimit;   // garbage lands only in discarded cols
      __builtin_amdgcn_global_load_lds((gvp)gp, (lvp)(l + r * 256), 16, 0, 0);
    }
  };

  // ---- compute-side fragment addressing ----
  const int ln = lane & 15, q = lane >> 4, g8 = q * 8;
  const unsigned short* ap = Ab + (size_t)ln * K + g8;
  int colp[4];
  #pragma unroll
  for (int s = 0; s < 4; ++s) colp[s] = (wv * 64 + s * 16 + ln + 8 * q) & 255;

  f32x4 acc[4][4];   // [mt][s]
  #pragma unroll
  for (int mt = 0; mt < 4; ++mt)
    #pragma unroll
    for (int s = 0; s < 4; ++s) acc[mt][s] = (f32x4){0.f, 0.f, 0.f, 0.f};

  stage(0, 0);
  for (int st = 0; st < NSTEP; ++st) {
    const int bf = st & 1;
    __syncthreads();                      // drains stage(bf); prev reads of bf^1 done
    if (st + 1 < NSTEP) stage(bf ^ 1, st + 1);

    const float* lb = &lw[bf][0];
    union { short8 v; unsigned short u[8]; } pb[4];
    #pragma unroll
    for (int s = 0; s < 4; ++s)
      #pragma unroll
      for (int j = 0; j < 8; ++j)
        pb[s].u[j] = f2bf(lb[(g8 + j) * 256 + colp[s]]);

    short8 afr[4];
    #pragma unroll
    for (int mt = 0; mt < 4; ++mt)
      afr[mt] = *reinterpret_cast<const short8*>(ap + (size_t)mt * 16 * K + st * 32);

    #pragma unroll
    for (int mt = 0; mt < 4; ++mt)
      #pragma unroll
      for (int s = 0; s < 4; ++s)
        acc[mt][s] = __builtin_amdgcn_mfma_f32_16x16x32_bf16(afr[mt], pb[s].v, acc[mt][s], 0, 0, 0);
  }

  // ---- epilogue: f32 partial store (C/D: col=ln, row=q*4+reg) ----
  float* op = outp + (size_t)(z * nbatch + bt) * 64 * N;
  #pragma unroll
  for (int mt = 0; mt < 4; ++mt)
    #pragma unroll
    for (int s = 0; s < 4; ++s) {
      const int col = n0 + wv * 64 + s * 16 + ln;
      if (NGUARD && col >= N) continue;
      #pragma unroll
      for (int r = 0; r < 4; ++r)
        op[(size_t)(mt * 16 + q * 4 + r) * N + col] = acc[mt][s][r];
    }
}

// ---------------------------------------------------------------------------
// Split-K reduce epilogue: out = act(sum_z part[z] + bias[bt][n])
// part layout [SPLIT][nbatch][64][N]
// ---------------------------------------------------------------------------
template<int SPLIT, bool GELU, bool OUTBF>
__global__ __launch_bounds__(256) void reduce_ep(
    const float* __restrict__ part, const float* __restrict__ bias,
    void* __restrict__ outv, const int N, const int nbatch)
{
  const int total = nbatch * 64 * N;
  const int idx = blockIdx.x * 256 + threadIdx.x;
  if (idx >= total) return;
  const int n = idx % N;
  const int bt = idx / (64 * N);
  float s = 0.f;
  #pragma unroll
  for (int zz = 0; zz < SPLIT; ++zz) s += part[(size_t)zz * total + idx];
  s += bias[(size_t)bt * N + n];
  if (GELU) s = gelu_f(s);
  if (OUTBF) ((unsigned short*)outv)[idx] = f2bf(s);
  else       ((float*)outv)[idx] = s;
}

// ---------------------------------------------------------------------------
// Fused sw-reduce + gate: t = gelu(sum_z tpt + sw_b1) (in-register),
// logits[e] = t . sw_w2[:,e] + sw_b2[e]; wout = softmax over e.
// ---------------------------------------------------------------------------
template<int SPLIT>
__global__ __launch_bounds__(256) void swgate2_kernel(
    const float* __restrict__ part, const float* __restrict__ b1,
    const float* __restrict__ w2, const float* __restrict__ b2,
    float* __restrict__ wout)
{
  __shared__ float red[256][8];
  const int b = blockIdx.x, tid = threadIdx.x;
  float p[8] = {0, 0, 0, 0, 0, 0, 0, 0};
  for (int i = tid; i < ND; i += 256) {
    float tv = b1[i];
    #pragma unroll
    for (int zz = 0; zz < SPLIT; ++zz)
      tv += part[(size_t)zz * (64 * ND) + (size_t)b * ND + i];
    tv = gelu_f(tv);
    const float4* wp = reinterpret_cast<const float4*>(w2 + (size_t)i * 8);
    const float4 wa = wp[0], wc = wp[1];
    p[0] += tv * wa.x; p[1] += tv * wa.y; p[2] += tv * wa.z; p[3] += tv * wa.w;
    p[4] += tv * wc.x; p[5] += tv * wc.y; p[6] += tv * wc.z; p[7] += tv * wc.w;
  }
  #pragma unroll
  for (int e = 0; e < 8; ++e) red[tid][e] = p[e];
  __syncthreads();
  for (int off = 128; off >= 1; off >>= 1) {
    if (tid < off) {
      #pragma unroll
      for (int e = 0; e < 8; ++e) red[tid][e] += red[tid + off][e];
    }
    __syncthreads();
  }
  if (tid == 0) {
    float lg[8];
    #pragma unroll
    for (int e = 0; e < 8; ++e) lg[e] = red[0][e] + b2[e];
    float mx = lg[0];
    #pragma unroll
    for (int e = 1; e < 8; ++e) mx = fmaxf(mx, lg[e]);
    float sum = 0.f;
    #pragma unroll
    for (int e = 0; e < 8; ++e) sum += expf(lg[e] - mx);
    #pragma unroll
    for (int e = 0; e < 8; ++e) wout[b * 8 + e] = expf(lg[e] - mx) / sum;
  }
}

// ---------------------------------------------------------------------------
// Fused expert-GEMM2 reduce + mix:
// ws[b][c] = sum_e wv[b][e] * (sum_z part[((z*8+e)*64+b)*KD + c] + b2[e][c])
// ---------------------------------------------------------------------------
template<int SPLIT>
__global__ __launch_bounds__(256) void mix2_kernel(
    const float* __restrict__ part, const float* __restrict__ b2,
    const float* __restrict__ wv, unsigned short* __restrict__ wsb)
{
  const int idx = blockIdx.x * 256 + threadIdx.x;   // 64*KD total
  const int b = idx / KD, c = idx % KD;
  float s = 0.f;
  #pragma unroll
  for (int e = 0; e < NE; ++e) {
    float v = b2[(size_t)e * KD + c];
    #pragma unroll
    for (int zz = 0; zz < SPLIT; ++zz)
      v += part[((size_t)(zz * NE + e) * NB + b) * KD + c];
    s += v * wv[b * NE + e];
  }
  wsb[idx] = f2bf(s);
}

// ---------------------------------------------------------------------------
extern "C" void kernel_launch(void* const* d_in, const int* in_sizes, int n_in,
                              void* d_out, int out_size, void* d_ws, size_t ws_size,
                              hipStream_t stream)
{
  (void)in_sizes; (void)n_in; (void)out_size; (void)ws_size;
  const float* x     = (const float*)d_in[0];
  const float* emb   = (const float*)d_in[1];
  const float* w1    = (const float*)d_in[2];
  const float* b1    = (const float*)d_in[3];
  const float* w2    = (const float*)d_in[4];
  const float* b2    = (const float*)d_in[5];
  const float* sw_w1 = (const float*)d_in[6];
  const float* sw_b1 = (const float*)d_in[7];
  const float* sw_w2 = (const float*)d_in[8];
  const float* sw_b2 = (const float*)d_in[9];
  const float* ch_w1 = (const float*)d_in[10];
  const float* ch_b1 = (const float*)d_in[11];
  const float* ch_w2 = (const float*)d_in[12];
  const float* ch_b2 = (const float*)d_in[13];
  float* out = (float*)d_out;

  char* ws = (char*)d_ws;
  size_t off = 0;
  auto alloc = [&](size_t bytes) -> void* {
    void* p = ws + off;
    off += (bytes + 255) & ~(size_t)255;
    return p;
  };
  unsigned short* sel  = (unsigned short*)alloc((size_t)NE * NB * KD * 2);  // bf16 (E,64,KD)
  unsigned short* xb   = (unsigned short*)alloc((size_t)NB * ND * 2);       // bf16 (64,ND)
  unsigned short* h    = (unsigned short*)alloc((size_t)NE * NB * KD * 2);  // bf16 (E,64,KD)
  float*          ep   = (float*)alloc((size_t)2 * NE * NB * KD * 4);       // expert partials (z2)
  float*          tpt  = (float*)alloc((size_t)4 * NB * ND * 4);            // sw1 partials (z4)
  float*          wv   = (float*)alloc((size_t)NB * NE * 4);                // gate weights
  unsigned short* wsb  = (unsigned short*)alloc((size_t)NB * KD * 2);       // bf16 (64,KD)
  float*          g1p  = (float*)alloc((size_t)16 * NB * KD * 4);           // ch1 partials (z16)
  unsigned short* g1   = (unsigned short*)alloc((size_t)NB * KD * 2);       // bf16 (64,KD)
  float*          g2p  = (float*)alloc((size_t)32 * NB * NC * 4);           // ch2 partials (z32)

  // 1) routing + gathers + bf16 casts
  routing_kernel<<<dim3(64), 256, 0, stream>>>(x, emb, sel, xb);
  // 2) expert GEMM1 partials: ep = sel @ w1 (z2)
  gemm3<KD, KD, 2, false><<<dim3(12, 8, 2), 256, 0, stream>>>(sel, w1, ep, 8);
  // 3) h = gelu(sum_z ep + b1)  [bf16]
  reduce_ep<2, true, true><<<dim3(6144), 256, 0, stream>>>(ep, b1, (void*)h, KD, 8);
  // 4) expert GEMM2 partials: ep = h @ w2 (z2)  [reuse buffer]
  gemm3<KD, KD, 2, false><<<dim3(12, 8, 2), 256, 0, stream>>>(h, w2, ep, 8);
  // 5) sw GEMM1 partials: tpt = xb @ sw_w1 (z4)
  gemm3<ND, ND, 4, false><<<dim3(48, 1, 4), 256, 0, stream>>>(xb, sw_w1, tpt, 1);
  // 6) fused sw-reduce + gate softmax
  swgate2_kernel<4><<<dim3(64), 256, 0, stream>>>(tpt, sw_b1, sw_w2, sw_b2, wv);
  // 7) ws = sum_e (sum_z ep + b2) * w  [bf16, fused reduce+mix]
  mix2_kernel<2><<<dim3((NB * KD) / 256), 256, 0, stream>>>(ep, b2, wv, wsb);
  // 8) ch GEMM1 partials: g1p = wsb @ ch_w1 (z16)
  gemm3<KD, KD, 16, false><<<dim3(12, 1, 16), 256, 0, stream>>>(wsb, ch_w1, g1p, 1);
  // 9) g1 = gelu(sum_z g1p + ch_b1)  [bf16]
  reduce_ep<16, true, true><<<dim3(768), 256, 0, stream>>>(g1p, ch_b1, (void*)g1, KD, 1);
  // 10) ch GEMM2 partials (N=1000, guarded): g2p = g1 @ ch_w2 (z32)
  gemm3<KD, NC, 32, true><<<dim3(4, 1, 32), 256, 0, stream>>>(g1, ch_w2, g2p, 1);
  // 11) out = sum_z g2p + ch_b2  [f32 -> d_out]
  reduce_ep<32, false, false><<<dim3((NB * NC + 255) / 256), 256, 0, stream>>>(g2p, ch_b2, (void*)out, NC, 1);
}

// Round 5
// 406.042 us; speedup vs baseline: 1.1011x; 1.1011x over previous
//
#include <hip/hip_runtime.h>
#include <hip/hip_bf16.h>

using short8 = __attribute__((ext_vector_type(8))) short;
using f32x4  = __attribute__((ext_vector_type(4))) float;

typedef const __attribute__((address_space(1))) void* gvp;
typedef __attribute__((address_space(3))) void* lvp;

#define NB   64     // batch rows (M)
#define NTOK 32     // tokens per batch row
#define DD   384
#define NE   8      // experts
#define TK   8      // top-k
#define NC   1000
#define KD   3072   // K*D
#define ND   12288  // N*D

__device__ __forceinline__ float gelu_f(float x) {
  return 0.5f * x * (1.0f + erff(x * 0.70710678118654752440f));
}

// f32 -> bf16 round-to-nearest-even (bit trick)
__device__ __forceinline__ unsigned short f2bf(float f) {
  unsigned u = __float_as_uint(f);
  u += 0x7fffu + ((u >> 16) & 1u);
  return (unsigned short)(u >> 16);
}

// ---------------------------------------------------------------------------
// Routing: logits = x[b] @ emb^T, top-8 per (b,e) (softmax monotonic -> skip),
// gather sel[e][b][k*D+d] = bf16(x[b][I[b,e,k]][d]); also xb = bf16(x).
// ---------------------------------------------------------------------------
__global__ __launch_bounds__(256) void routing_kernel(
    const float* __restrict__ x, const float* __restrict__ emb,
    unsigned short* __restrict__ sel, unsigned short* __restrict__ xb)
{
  __shared__ float xs[NTOK][DD + 1];   // +1 pad: kill stride-384 bank conflicts
  __shared__ float es[NE][DD + 1];
  __shared__ float lg[NE][NTOK];
  __shared__ int   Is[NE][TK];
  const int b = blockIdx.x, tid = threadIdx.x;

  for (int i = tid; i < NTOK * DD; i += 256) xs[i / DD][i % DD] = x[(size_t)b * ND + i];
  for (int i = tid; i < NE * DD;   i += 256) es[i / DD][i % DD] = emb[i];
  __syncthreads();

  {
    const int e = tid >> 5, n = tid & 31;
    float s = 0.f;
    for (int d = 0; d < DD; ++d) s += xs[n][d] * es[e][d];
    lg[e][n] = s;
  }
  __syncthreads();

  if (tid < NE) {   // stable argmax x8: ties -> lowest index, matches lax.top_k
    const int e = tid;
    for (int k = 0; k < TK; ++k) {
      float best = lg[e][0]; int bi = 0;
      for (int n = 1; n < NTOK; ++n) { float v = lg[e][n]; if (v > best) { best = v; bi = n; } }
      Is[e][k] = bi;
      lg[e][bi] = -INFINITY;
    }
  }
  __syncthreads();

  for (int i = tid; i < NE * KD; i += 256) {
    const int e = i / KD, r = i % KD, k = r / DD, d = r % DD;
    const int n = Is[e][k];
    sel[((size_t)e * NB + b) * KD + r] = f2bf(xs[n][d]);
  }
  for (int i = tid; i < ND; i += 256) xb[(size_t)b * ND + i] = f2bf(xs[i / DD][i % DD]);
}

// ---------------------------------------------------------------------------
// Skinny GEMM v4b: partial[z] = A(bf16,[64][K])[:, z-slice] @ W(f32 slice)
// 64x128 tile, 16KB staging steps, 3-buffer LDS ring (48KB -> 3 blocks/CU).
// Counted-vmcnt pipeline. Correctness argument:
//  - each body starts with asm volatile waitcnt + "memory" clobber; no memory
//    op can cross it, so ops issued between consecutive body entries = exactly
//    {stage(st+2)(4), aload(st+1)(4)} in SOME order -> the newest-8 SET at
//    body(st) entry is fixed -> vmcnt(8) always retires stage(st).
//  - body(0): prologue order is not fenced (pure aload can hoist above the
//    stage builtins) -> use vmcnt(0) once (full drain, amortized 1/NSTEP).
//  - last body: only aload(NSTEP-1)(4) was issued by previous body -> vmcnt(4).
// Rotation swizzle (8 floats per 8-row group) applied on the global SOURCE
// address (linear LDS dest, per m173), same rotation on the read side ->
// exact 2-way bank aliasing (free). f32 partials out; bias/act in epilogue.
// ---------------------------------------------------------------------------
template<int K, int N, int SPLIT, bool NGUARD>
__global__ __launch_bounds__(256) void gemm4(
    const unsigned short* __restrict__ A, const float* __restrict__ W,
    float* __restrict__ outp, const int nbatch)
{
  constexpr int KCH = K / SPLIT;
  constexpr int NSTEP = KCH / 32;
  static_assert(KCH % 32 == 0, "KCH must be a multiple of 32");
  __shared__ float lw[3][4096];      // 3 x [32 rows x 128 cols] f32 = 48KB

  const int t = threadIdx.x;
  const int wv = t >> 6, lane = t & 63;
  const int n0 = blockIdx.x * 128;
  const int bt = blockIdx.y, z = blockIdx.z;

  const unsigned short* Ab = A + (size_t)bt * 64 * K + (size_t)z * KCH;
  const float*          Wb = W + (size_t)bt * (size_t)K * N;

  // ---- staging geometry (proven in r2: 0 bank conflicts) ----
  // instr r of wave wv: rows wv*8 + r*2 + (lane>>5), stored col (lane&31)*4
  // source col = (stored - wv*8) & 127
  const int srow = wv * 8 + (lane >> 5);
  const int scol = (((lane & 31) * 4) - wv * 8) & 127;
  const float* gsrc   = Wb + (size_t)(z * KCH + srow) * N + n0 + scol;
  const float* glimit = Wb + (size_t)K * N - 4;   // OOB clamp (NGUARD)
  float* lbase = &lw[0][0] + wv * 1024 + lane * 4;

  auto stage = [&](int bf, int st) {
    const float* g = gsrc + (size_t)st * 32 * N;
    float* l = lbase + bf * 4096;
    #pragma unroll
    for (int r = 0; r < 4; ++r) {
      const float* gp = g + (size_t)(r * 2) * N;
      if (NGUARD && gp > glimit) gp = glimit;   // garbage lands only in discarded cols
      __builtin_amdgcn_global_load_lds((gvp)gp, (lvp)(l + r * 256), 16, 0, 0);
    }
  };

  // ---- compute-side fragment addressing ----
  const int ln = lane & 15, q = lane >> 4, g8 = q * 8;
  const unsigned short* ap = Ab + (size_t)ln * K + g8;
  const int colp0 = (wv * 32 +      ln + g8) & 127;   // rotated col, subtile 0
  const int colp1 = (wv * 32 + 16 + ln + g8) & 127;   // rotated col, subtile 1

  f32x4 acc[4][2];
  #pragma unroll
  for (int mt = 0; mt < 4; ++mt) {
    acc[mt][0] = (f32x4){0.f, 0.f, 0.f, 0.f};
    acc[mt][1] = (f32x4){0.f, 0.f, 0.f, 0.f};
  }

  short8 afrA[4], afrB[4];
  auto aload = [&](short8* dst, int st) {
    #pragma unroll
    for (int mt = 0; mt < 4; ++mt)
      dst[mt] = *reinterpret_cast<const short8*>(ap + (size_t)mt * 16 * K + st * 32);
  };

  int cbuf = 0, sbuf = 2;
  auto body = [&](int st, const short8* acur, short8* anext) {
    // retire stage(st): vmcnt(0) once at st==0 (prologue order unfenced),
    // vmcnt(4) at the tail (only aload(NSTEP-1) younger), else vmcnt(8).
    if (st == 0)                 asm volatile("s_waitcnt vmcnt(0)" ::: "memory");
    else if (st + 1 == NSTEP)    asm volatile("s_waitcnt vmcnt(4)" ::: "memory");
    else                         asm volatile("s_waitcnt vmcnt(8)" ::: "memory");
    __builtin_amdgcn_s_barrier();     // raw: no compiler vmcnt(0) drain
    if (st + 2 < NSTEP) stage(sbuf, st + 2);
    if (st + 1 < NSTEP) aload(anext, st + 1);

    const float* lb = &lw[0][0] + cbuf * 4096;
    union { short8 v; unsigned short u[8]; } pb0, pb1;
    #pragma unroll
    for (int j = 0; j < 8; ++j) {
      pb0.u[j] = f2bf(lb[(g8 + j) * 128 + colp0]);
      pb1.u[j] = f2bf(lb[(g8 + j) * 128 + colp1]);
    }
    #pragma unroll
    for (int mt = 0; mt < 4; ++mt) {
      acc[mt][0] = __builtin_amdgcn_mfma_f32_16x16x32_bf16(acur[mt], pb0.v, acc[mt][0], 0, 0, 0);
      acc[mt][1] = __builtin_amdgcn_mfma_f32_16x16x32_bf16(acur[mt], pb1.v, acc[mt][1], 0, 0, 0);
    }
    cbuf = (cbuf == 2) ? 0 : cbuf + 1;
    sbuf = (sbuf == 2) ? 0 : sbuf + 1;
  };

  // prologue: stage(0), stage(1), then A(0); sched_barrier pins issue order
  stage(0, 0);
  if (NSTEP > 1) stage(1, 1);
  __builtin_amdgcn_sched_barrier(0);
  aload(afrA, 0);

  for (int st = 0; st < NSTEP; st += 2) {
    body(st, afrA, afrB);
    if (st + 1 < NSTEP) body(st + 1, afrB, afrA);
  }

  // ---- epilogue: f32 partial store (C/D: col=ln, row=q*4+reg) ----
  float* op = outp + (size_t)(z * nbatch + bt) * 64 * N;
  #pragma unroll
  for (int mt = 0; mt < 4; ++mt)
    #pragma unroll
    for (int s = 0; s < 2; ++s) {
      const int col = n0 + wv * 32 + s * 16 + ln;
      if (NGUARD && col >= N) continue;
      #pragma unroll
      for (int r = 0; r < 4; ++r)
        op[(size_t)(mt * 16 + q * 4 + r) * N + col] = acc[mt][s][r];
    }
}

// ---------------------------------------------------------------------------
// Split-K reduce epilogue: out = act(sum_z part[z] + bias[bt][n])
// part layout [SPLIT][nbatch][64][N]
// ---------------------------------------------------------------------------
template<int SPLIT, bool GELU, bool OUTBF>
__global__ __launch_bounds__(256) void reduce_ep(
    const float* __restrict__ part, const float* __restrict__ bias,
    void* __restrict__ outv, const int N, const int nbatch)
{
  const int total = nbatch * 64 * N;
  const int idx = blockIdx.x * 256 + threadIdx.x;
  if (idx >= total) return;
  const int n = idx % N;
  const int bt = idx / (64 * N);
  float s = 0.f;
  #pragma unroll
  for (int zz = 0; zz < SPLIT; ++zz) s += part[(size_t)zz * total + idx];
  s += bias[(size_t)bt * N + n];
  if (GELU) s = gelu_f(s);
  if (OUTBF) ((unsigned short*)outv)[idx] = f2bf(s);
  else       ((float*)outv)[idx] = s;
}

// ---------------------------------------------------------------------------
// Fused sw-reduce + gate: t = gelu(sum_z tpt + sw_b1) (in-register),
// logits[e] = t . sw_w2[:,e] + sw_b2[e]; wout = softmax over e.
// ---------------------------------------------------------------------------
template<int SPLIT>
__global__ __launch_bounds__(256) void swgate2_kernel(
    const float* __restrict__ part, const float* __restrict__ b1,
    const float* __restrict__ w2, const float* __restrict__ b2,
    float* __restrict__ wout)
{
  __shared__ float red[256][8];
  const int b = blockIdx.x, tid = threadIdx.x;
  float p[8] = {0, 0, 0, 0, 0, 0, 0, 0};
  for (int i = tid; i < ND; i += 256) {
    float tv = b1[i];
    #pragma unroll
    for (int zz = 0; zz < SPLIT; ++zz)
      tv += part[(size_t)zz * (64 * ND) + (size_t)b * ND + i];
    tv = gelu_f(tv);
    const float4* wp = reinterpret_cast<const float4*>(w2 + (size_t)i * 8);
    const float4 wa = wp[0], wc = wp[1];
    p[0] += tv * wa.x; p[1] += tv * wa.y; p[2] += tv * wa.z; p[3] += tv * wa.w;
    p[4] += tv * wc.x; p[5] += tv * wc.y; p[6] += tv * wc.z; p[7] += tv * wc.w;
  }
  #pragma unroll
  for (int e = 0; e < 8; ++e) red[tid][e] = p[e];
  __syncthreads();
  for (int off = 128; off >= 1; off >>= 1) {
    if (tid < off) {
      #pragma unroll
      for (int e = 0; e < 8; ++e) red[tid][e] += red[tid + off][e];
    }
    __syncthreads();
  }
  if (tid == 0) {
    float lg[8];
    #pragma unroll
    for (int e = 0; e < 8; ++e) lg[e] = red[0][e] + b2[e];
    float mx = lg[0];
    #pragma unroll
    for (int e = 1; e < 8; ++e) mx = fmaxf(mx, lg[e]);
    float sum = 0.f;
    #pragma unroll
    for (int e = 0; e < 8; ++e) sum += expf(lg[e] - mx);
    #pragma unroll
    for (int e = 0; e < 8; ++e) wout[b * 8 + e] = expf(lg[e] - mx) / sum;
  }
}

// ---------------------------------------------------------------------------
// Fused expert-GEMM2 reduce + mix:
// ws[b][c] = sum_e wv[b][e] * (sum_z part[((z*8+e)*64+b)*KD + c] + b2[e][c])
// ---------------------------------------------------------------------------
template<int SPLIT>
__global__ __launch_bounds__(256) void mix2_kernel(
    const float* __restrict__ part, const float* __restrict__ b2,
    const float* __restrict__ wv, unsigned short* __restrict__ wsb)
{
  const int idx = blockIdx.x * 256 + threadIdx.x;   // 64*KD total
  const int b = idx / KD, c = idx % KD;
  float s = 0.f;
  #pragma unroll
  for (int e = 0; e < NE; ++e) {
    float v = b2[(size_t)e * KD + c];
    #pragma unroll
    for (int zz = 0; zz < SPLIT; ++zz)
      v += part[((size_t)(zz * NE + e) * NB + b) * KD + c];
    s += v * wv[b * NE + e];
  }
  wsb[idx] = f2bf(s);
}

// ---------------------------------------------------------------------------
extern "C" void kernel_launch(void* const* d_in, const int* in_sizes, int n_in,
                              void* d_out, int out_size, void* d_ws, size_t ws_size,
                              hipStream_t stream)
{
  (void)in_sizes; (void)n_in; (void)out_size; (void)ws_size;
  const float* x     = (const float*)d_in[0];
  const float* emb   = (const float*)d_in[1];
  const float* w1    = (const float*)d_in[2];
  const float* b1    = (const float*)d_in[3];
  const float* w2    = (const float*)d_in[4];
  const float* b2    = (const float*)d_in[5];
  const float* sw_w1 = (const float*)d_in[6];
  const float* sw_b1 = (const float*)d_in[7];
  const float* sw_w2 = (const float*)d_in[8];
  const float* sw_b2 = (const float*)d_in[9];
  const float* ch_w1 = (const float*)d_in[10];
  const float* ch_b1 = (const float*)d_in[11];
  const float* ch_w2 = (const float*)d_in[12];
  const float* ch_b2 = (const float*)d_in[13];
  float* out = (float*)d_out;

  char* ws = (char*)d_ws;
  size_t off = 0;
  auto alloc = [&](size_t bytes) -> void* {
    void* p = ws + off;
    off += (bytes + 255) & ~(size_t)255;
    return p;
  };
  unsigned short* sel  = (unsigned short*)alloc((size_t)NE * NB * KD * 2);  // bf16 (E,64,KD)
  unsigned short* xb   = (unsigned short*)alloc((size_t)NB * ND * 2);       // bf16 (64,ND)
  unsigned short* h    = (unsigned short*)alloc((size_t)NE * NB * KD * 2);  // bf16 (E,64,KD)
  float*          ep   = (float*)alloc((size_t)4 * NE * NB * KD * 4);       // expert partials (z4)
  float*          tpt  = (float*)alloc((size_t)8 * NB * ND * 4);            // sw1 partials (z8)
  float*          wv   = (float*)alloc((size_t)NB * NE * 4);                // gate weights
  unsigned short* wsb  = (unsigned short*)alloc((size_t)NB * KD * 2);       // bf16 (64,KD)
  float*          g1p  = (float*)alloc((size_t)16 * NB * KD * 4);           // ch1 partials (z16)
  unsigned short* g1   = (unsigned short*)alloc((size_t)NB * KD * 2);       // bf16 (64,KD)
  float*          g2p  = (float*)alloc((size_t)32 * NB * NC * 4);           // ch2 partials (z32)

  // 1) routing + gathers + bf16 casts
  routing_kernel<<<dim3(64), 256, 0, stream>>>(x, emb, sel, xb);
  // 2) expert GEMM1 partials: ep = sel @ w1 (z4, 768 blocks)
  gemm4<KD, KD, 4, false><<<dim3(24, 8, 4), 256, 0, stream>>>(sel, w1, ep, 8);
  // 3) h = gelu(sum_z ep + b1)  [bf16]
  reduce_ep<4, true, true><<<dim3(6144), 256, 0, stream>>>(ep, b1, (void*)h, KD, 8);
  // 4) expert GEMM2 partials: ep = h @ w2 (z4, 768 blocks)  [reuse buffer]
  gemm4<KD, KD, 4, false><<<dim3(24, 8, 4), 256, 0, stream>>>(h, w2, ep, 8);
  // 5) sw GEMM1 partials: tpt = xb @ sw_w1 (z8, 768 blocks)
  gemm4<ND, ND, 8, false><<<dim3(96, 1, 8), 256, 0, stream>>>(xb, sw_w1, tpt, 1);
  // 6) fused sw-reduce + gate softmax
  swgate2_kernel<8><<<dim3(64), 256, 0, stream>>>(tpt, sw_b1, sw_w2, sw_b2, wv);
  // 7) ws = sum_e (sum_z ep + b2) * w  [bf16, fused reduce+mix]
  mix2_kernel<4><<<dim3((NB * KD) / 256), 256, 0, stream>>>(ep, b2, wv, wsb);
  // 8) ch GEMM1 partials: g1p = wsb @ ch_w1 (z16, 384 blocks)
  gemm4<KD, KD, 16, false><<<dim3(24, 1, 16), 256, 0, stream>>>(wsb, ch_w1, g1p, 1);
  // 9) g1 = gelu(sum_z g1p + ch_b1)  [bf16]
  reduce_ep<16, true, true><<<dim3(768), 256, 0, stream>>>(g1p, ch_b1, (void*)g1, KD, 1);
  // 10) ch GEMM2 partials (N=1000, guarded): g2p = g1 @ ch_w2 (z32, 256 blocks)
  gemm4<KD, NC, 32, true><<<dim3(8, 1, 32), 256, 0, stream>>>(g1, ch_w2, g2p, 1);
  // 11) out = sum_z g2p + ch_b2  [f32 -> d_out]
  reduce_ep<32, false, false><<<dim3((NB * NC + 255) / 256), 256, 0, stream>>>(g2p, ch_b2, (void*)out, NC, 1);
}

// Round 6
// 378.219 us; speedup vs baseline: 1.1821x; 1.0736x over previous
//
#include <hip/hip_runtime.h>
#include <hip/hip_bf16.h>

using short8 = __attribute__((ext_vector_type(8))) short;
using f32x4  = __attribute__((ext_vector_type(4))) float;

typedef const __attribute__((address_space(1))) void* gvp;
typedef __attribute__((address_space(3))) void* lvp;

#define NB   64     // batch rows (M)
#define NTOK 32     // tokens per batch row
#define DD   384
#define NE   8      // experts
#define TK   8      // top-k
#define NC   1000
#define KD   3072   // K*D
#define ND   12288  // N*D

__device__ __forceinline__ float gelu_f(float x) {
  return 0.5f * x * (1.0f + erff(x * 0.70710678118654752440f));
}

// f32 -> bf16 round-to-nearest-even (bit trick)
__device__ __forceinline__ unsigned short f2bf(float f) {
  unsigned u = __float_as_uint(f);
  u += 0x7fffu + ((u >> 16) & 1u);
  return (unsigned short)(u >> 16);
}

// ---------------------------------------------------------------------------
// Routing: logits = x[b] @ emb^T, top-8 per (b,e) (softmax monotonic -> skip),
// gather sel[e][b][k*D+d] = bf16(x[b][I[b,e,k]][d]); also xb = bf16(x).
// ---------------------------------------------------------------------------
__global__ __launch_bounds__(256) void routing_kernel(
    const float* __restrict__ x, const float* __restrict__ emb,
    unsigned short* __restrict__ sel, unsigned short* __restrict__ xb)
{
  __shared__ float xs[NTOK][DD + 1];   // +1 pad: kill stride-384 bank conflicts
  __shared__ float es[NE][DD + 1];
  __shared__ float lg[NE][NTOK];
  __shared__ int   Is[NE][TK];
  const int b = blockIdx.x, tid = threadIdx.x;

  for (int i = tid; i < NTOK * DD; i += 256) xs[i / DD][i % DD] = x[(size_t)b * ND + i];
  for (int i = tid; i < NE * DD;   i += 256) es[i / DD][i % DD] = emb[i];
  __syncthreads();

  {
    const int e = tid >> 5, n = tid & 31;
    float s = 0.f;
    for (int d = 0; d < DD; ++d) s += xs[n][d] * es[e][d];
    lg[e][n] = s;
  }
  __syncthreads();

  if (tid < NE) {   // stable argmax x8: ties -> lowest index, matches lax.top_k
    const int e = tid;
    for (int k = 0; k < TK; ++k) {
      float best = lg[e][0]; int bi = 0;
      for (int n = 1; n < NTOK; ++n) { float v = lg[e][n]; if (v > best) { best = v; bi = n; } }
      Is[e][k] = bi;
      lg[e][bi] = -INFINITY;
    }
  }
  __syncthreads();

  for (int i = tid; i < NE * KD; i += 256) {
    const int e = i / KD, r = i % KD, k = r / DD, d = r % DD;
    const int n = Is[e][k];
    sel[((size_t)e * NB + b) * KD + r] = f2bf(xs[n][d]);
  }
  for (int i = tid; i < ND; i += 256) xb[(size_t)b * ND + i] = f2bf(xs[i / DD][i % DD]);
}

// ---------------------------------------------------------------------------
// Skinny GEMM v3 (r3 kernel, proven correct; now launched with grids >= 256):
// partial[z] = A(bf16,[64][K])[:, z-slice] @ W(f32 slice)
// Block tile 64x256, staging steps of 32 rows x 256 cols (32 KB), double-
// buffered (64 KB LDS, 2 blocks/CU). Each global_load_lds call stages ONE
// FULL 1KB contiguous row (DRAM page granularity test). 8-float rotation
// per 8-row group applied on the SOURCE address (linear LDS dest, m173),
// matching rotation on the read side -> exact 2-way bank aliasing (free).
// 4 waves split n (64 cols each, 4 subtiles of 16). f32 partials out.
// ---------------------------------------------------------------------------
template<int K, int N, int SPLIT, bool NGUARD>
__global__ __launch_bounds__(256) void gemm3(
    const unsigned short* __restrict__ A, const float* __restrict__ W,
    float* __restrict__ outp, const int nbatch)
{
  constexpr int KCH = K / SPLIT;
  constexpr int NSTEP = KCH / 32;
  static_assert(KCH % 32 == 0, "KCH must be a multiple of 32");
  __shared__ float lw[2][8192];      // [buf][32 rows x 256 cols] f32

  const int t = threadIdx.x;
  const int wv = t >> 6, lane = t & 63;
  const int n0 = blockIdx.x * 256;
  const int bt = blockIdx.y, z = blockIdx.z;

  const unsigned short* Ab = A + (size_t)bt * 64 * K + (size_t)z * KCH;
  const float*          Wb = W + (size_t)bt * (size_t)K * N;

  // ---- staging: wave wv fills rows wv*8 .. wv*8+7 of each 32-row step ----
  // call r: full row (wv*8+r), lane writes stored cols lane*4..+3;
  // source col = (lane*4 - rot(row)) & 255, rot(row) = (row>>3)*8 = wv*8
  const int scol = ((lane * 4) - wv * 8) & 255;
  const float* gsrc   = Wb + (size_t)(z * KCH + wv * 8) * N + n0 + scol;
  const float* glimit = Wb + (size_t)K * N - 4;   // OOB clamp (NGUARD)
  float* lbase = &lw[0][0] + (wv * 8) * 256 + lane * 4;

  auto stage = [&](int bf, int st) {
    const float* g = gsrc + (size_t)st * 32 * N;
    float* l = lbase + bf * 8192;
    #pragma unroll
    for (int r = 0; r < 8; ++r) {
      const float* gp = g + (size_t)r * N;
      if (NGUARD && gp > glimit) gp = glimit;   // garbage lands only in discarded cols
      __builtin_amdgcn_global_load_lds((gvp)gp, (lvp)(l + r * 256), 16, 0, 0);
    }
  };

  // ---- compute-side fragment addressing ----
  const int ln = lane & 15, q = lane >> 4, g8 = q * 8;
  const unsigned short* ap = Ab + (size_t)ln * K + g8;
  int colp[4];
  #pragma unroll
  for (int s = 0; s < 4; ++s) colp[s] = (wv * 64 + s * 16 + ln + 8 * q) & 255;

  f32x4 acc[4][4];   // [mt][s]
  #pragma unroll
  for (int mt = 0; mt < 4; ++mt)
    #pragma unroll
    for (int s = 0; s < 4; ++s) acc[mt][s] = (f32x4){0.f, 0.f, 0.f, 0.f};

  stage(0, 0);
  for (int st = 0; st < NSTEP; ++st) {
    const int bf = st & 1;
    __syncthreads();                      // drains stage(bf); prev reads of bf^1 done
    if (st + 1 < NSTEP) stage(bf ^ 1, st + 1);

    const float* lb = &lw[bf][0];
    union { short8 v; unsigned short u[8]; } pb[4];
    #pragma unroll
    for (int s = 0; s < 4; ++s)
      #pragma unroll
      for (int j = 0; j < 8; ++j)
        pb[s].u[j] = f2bf(lb[(g8 + j) * 256 + colp[s]]);

    short8 afr[4];
    #pragma unroll
    for (int mt = 0; mt < 4; ++mt)
      afr[mt] = *reinterpret_cast<const short8*>(ap + (size_t)mt * 16 * K + st * 32);

    #pragma unroll
    for (int mt = 0; mt < 4; ++mt)
      #pragma unroll
      for (int s = 0; s < 4; ++s)
        acc[mt][s] = __builtin_amdgcn_mfma_f32_16x16x32_bf16(afr[mt], pb[s].v, acc[mt][s], 0, 0, 0);
  }

  // ---- epilogue: f32 partial store (C/D: col=ln, row=q*4+reg) ----
  float* op = outp + (size_t)(z * nbatch + bt) * 64 * N;
  #pragma unroll
  for (int mt = 0; mt < 4; ++mt)
    #pragma unroll
    for (int s = 0; s < 4; ++s) {
      const int col = n0 + wv * 64 + s * 16 + ln;
      if (NGUARD && col >= N) continue;
      #pragma unroll
      for (int r = 0; r < 4; ++r)
        op[(size_t)(mt * 16 + q * 4 + r) * N + col] = acc[mt][s][r];
    }
}

// ---------------------------------------------------------------------------
// Split-K reduce epilogue: out = act(sum_z part[z] + bias[bt][n])
// part layout [SPLIT][nbatch][64][N]
// ---------------------------------------------------------------------------
template<int SPLIT, bool GELU, bool OUTBF>
__global__ __launch_bounds__(256) void reduce_ep(
    const float* __restrict__ part, const float* __restrict__ bias,
    void* __restrict__ outv, const int N, const int nbatch)
{
  const int total = nbatch * 64 * N;
  const int idx = blockIdx.x * 256 + threadIdx.x;
  if (idx >= total) return;
  const int n = idx % N;
  const int bt = idx / (64 * N);
  float s = 0.f;
  #pragma unroll
  for (int zz = 0; zz < SPLIT; ++zz) s += part[(size_t)zz * total + idx];
  s += bias[(size_t)bt * N + n];
  if (GELU) s = gelu_f(s);
  if (OUTBF) ((unsigned short*)outv)[idx] = f2bf(s);
  else       ((float*)outv)[idx] = s;
}

// ---------------------------------------------------------------------------
// Fused sw-reduce + gate: t = gelu(sum_z tpt + sw_b1) (in-register),
// logits[e] = t . sw_w2[:,e] + sw_b2[e]; wout = softmax over e.
// ---------------------------------------------------------------------------
template<int SPLIT>
__global__ __launch_bounds__(256) void swgate2_kernel(
    const float* __restrict__ part, const float* __restrict__ b1,
    const float* __restrict__ w2, const float* __restrict__ b2,
    float* __restrict__ wout)
{
  __shared__ float red[256][8];
  const int b = blockIdx.x, tid = threadIdx.x;
  float p[8] = {0, 0, 0, 0, 0, 0, 0, 0};
  for (int i = tid; i < ND; i += 256) {
    float tv = b1[i];
    #pragma unroll
    for (int zz = 0; zz < SPLIT; ++zz)
      tv += part[(size_t)zz * (64 * ND) + (size_t)b * ND + i];
    tv = gelu_f(tv);
    const float4* wp = reinterpret_cast<const float4*>(w2 + (size_t)i * 8);
    const float4 wa = wp[0], wc = wp[1];
    p[0] += tv * wa.x; p[1] += tv * wa.y; p[2] += tv * wa.z; p[3] += tv * wa.w;
    p[4] += tv * wc.x; p[5] += tv * wc.y; p[6] += tv * wc.z; p[7] += tv * wc.w;
  }
  #pragma unroll
  for (int e = 0; e < 8; ++e) red[tid][e] = p[e];
  __syncthreads();
  for (int off = 128; off >= 1; off >>= 1) {
    if (tid < off) {
      #pragma unroll
      for (int e = 0; e < 8; ++e) red[tid][e] += red[tid + off][e];
    }
    __syncthreads();
  }
  if (tid == 0) {
    float lg[8];
    #pragma unroll
    for (int e = 0; e < 8; ++e) lg[e] = red[0][e] + b2[e];
    float mx = lg[0];
    #pragma unroll
    for (int e = 1; e < 8; ++e) mx = fmaxf(mx, lg[e]);
    float sum = 0.f;
    #pragma unroll
    for (int e = 0; e < 8; ++e) sum += expf(lg[e] - mx);
    #pragma unroll
    for (int e = 0; e < 8; ++e) wout[b * 8 + e] = expf(lg[e] - mx) / sum;
  }
}

// ---------------------------------------------------------------------------
// Fused expert-GEMM2 reduce + mix:
// ws[b][c] = sum_e wv[b][e] * (sum_z part[((z*8+e)*64+b)*KD + c] + b2[e][c])
// ---------------------------------------------------------------------------
template<int SPLIT>
__global__ __launch_bounds__(256) void mix2_kernel(
    const float* __restrict__ part, const float* __restrict__ b2,
    const float* __restrict__ wv, unsigned short* __restrict__ wsb)
{
  const int idx = blockIdx.x * 256 + threadIdx.x;   // 64*KD total
  const int b = idx / KD, c = idx % KD;
  float s = 0.f;
  #pragma unroll
  for (int e = 0; e < NE; ++e) {
    float v = b2[(size_t)e * KD + c];
    #pragma unroll
    for (int zz = 0; zz < SPLIT; ++zz)
      v += part[((size_t)(zz * NE + e) * NB + b) * KD + c];
    s += v * wv[b * NE + e];
  }
  wsb[idx] = f2bf(s);
}

// ---------------------------------------------------------------------------
extern "C" void kernel_launch(void* const* d_in, const int* in_sizes, int n_in,
                              void* d_out, int out_size, void* d_ws, size_t ws_size,
                              hipStream_t stream)
{
  (void)in_sizes; (void)n_in; (void)out_size; (void)ws_size;
  const float* x     = (const float*)d_in[0];
  const float* emb   = (const float*)d_in[1];
  const float* w1    = (const float*)d_in[2];
  const float* b1    = (const float*)d_in[3];
  const float* w2    = (const float*)d_in[4];
  const float* b2    = (const float*)d_in[5];
  const float* sw_w1 = (const float*)d_in[6];
  const float* sw_b1 = (const float*)d_in[7];
  const float* sw_w2 = (const float*)d_in[8];
  const float* sw_b2 = (const float*)d_in[9];
  const float* ch_w1 = (const float*)d_in[10];
  const float* ch_b1 = (const float*)d_in[11];
  const float* ch_w2 = (const float*)d_in[12];
  const float* ch_b2 = (const float*)d_in[13];
  float* out = (float*)d_out;

  char* ws = (char*)d_ws;
  size_t off = 0;
  auto alloc = [&](size_t bytes) -> void* {
    void* p = ws + off;
    off += (bytes + 255) & ~(size_t)255;
    return p;
  };
  unsigned short* sel  = (unsigned short*)alloc((size_t)NE * NB * KD * 2);  // bf16 (E,64,KD)
  unsigned short* xb   = (unsigned short*)alloc((size_t)NB * ND * 2);       // bf16 (64,ND)
  unsigned short* h    = (unsigned short*)alloc((size_t)NE * NB * KD * 2);  // bf16 (E,64,KD)
  float*          ep   = (float*)alloc((size_t)4 * NE * NB * KD * 4);       // expert partials (z4)
  float*          tpt  = (float*)alloc((size_t)8 * NB * ND * 4);            // sw1 partials (z8)
  float*          wv   = (float*)alloc((size_t)NB * NE * 4);                // gate weights
  unsigned short* wsb  = (unsigned short*)alloc((size_t)NB * KD * 2);       // bf16 (64,KD)
  float*          g1p  = (float*)alloc((size_t)16 * NB * KD * 4);           // ch1 partials (z16)
  unsigned short* g1   = (unsigned short*)alloc((size_t)NB * KD * 2);       // bf16 (64,KD)
  float*          g2p  = (float*)alloc((size_t)32 * NB * NC * 4);           // ch2 partials (z32)

  // 1) routing + gathers + bf16 casts
  routing_kernel<<<dim3(64), 256, 0, stream>>>(x, emb, sel, xb);
  // 2) expert GEMM1 partials: ep = sel @ w1 (z4, 384 blocks, NSTEP=24)
  gemm3<KD, KD, 4, false><<<dim3(12, 8, 4), 256, 0, stream>>>(sel, w1, ep, 8);
  // 3) h = gelu(sum_z ep + b1)  [bf16]
  reduce_ep<4, true, true><<<dim3(6144), 256, 0, stream>>>(ep, b1, (void*)h, KD, 8);
  // 4) expert GEMM2 partials: ep = h @ w2 (z4, 384 blocks)  [reuse buffer]
  gemm3<KD, KD, 4, false><<<dim3(12, 8, 4), 256, 0, stream>>>(h, w2, ep, 8);
  // 5) sw GEMM1 partials: tpt = xb @ sw_w1 (z8, 384 blocks, NSTEP=48)
  gemm3<ND, ND, 8, false><<<dim3(48, 1, 8), 256, 0, stream>>>(xb, sw_w1, tpt, 1);
  // 6) fused sw-reduce + gate softmax
  swgate2_kernel<8><<<dim3(64), 256, 0, stream>>>(tpt, sw_b1, sw_w2, sw_b2, wv);
  // 7) ws = sum_e (sum_z ep + b2) * w  [bf16, fused reduce+mix]
  mix2_kernel<4><<<dim3((NB * KD) / 256), 256, 0, stream>>>(ep, b2, wv, wsb);
  // 8) ch GEMM1 partials: g1p = wsb @ ch_w1 (z16, 192 blocks, NSTEP=6)
  gemm3<KD, KD, 16, false><<<dim3(12, 1, 16), 256, 0, stream>>>(wsb, ch_w1, g1p, 1);
  // 9) g1 = gelu(sum_z g1p + ch_b1)  [bf16]
  reduce_ep<16, true, true><<<dim3(768), 256, 0, stream>>>(g1p, ch_b1, (void*)g1, KD, 1);
  // 10) ch GEMM2 partials (N=1000, guarded): g2p = g1 @ ch_w2 (z32, 128 blocks)
  gemm3<KD, NC, 32, true><<<dim3(4, 1, 32), 256, 0, stream>>>(g1, ch_w2, g2p, 1);
  // 11) out = sum_z g2p + ch_b2  [f32 -> d_out]
  reduce_ep<32, false, false><<<dim3((NB * NC + 255) / 256), 256, 0, stream>>>(g2p, ch_b2, (void*)out, NC, 1);
}